// Round 1
// baseline (50.730 us; speedup 1.0000x reference)
//
#include <hip/hip_runtime.h>

// BinaryTreeRNN: per row n of x (N x 16, f32):
//   h[l] = leaf_w[l,:] . x[n,:] + leaf_b[l]         (8 leaves)
//   3 tree levels (om3/w3/b3 -> om2/w2/b2 -> om1/w1/b1), each node:
//     s = l + r; out = w*(w0*s + w1*sin s + w2*cos s + w3*l*r) + b
//   with (w0..w3) = softmax(om row). Output h[0] : (N,) f32.
//
// Node coefficients (7 nodes x {c0..c3=w*softmax(om), c4=b}) are precomputed
// into d_ws by a tiny kernel so the main kernel reads them (and leaf_w/leaf_b)
// via wave-uniform scalar loads. Memory-bound: 272 MB traffic -> ~43 us floor.

__device__ __forceinline__ float node_eval(float l, float r, const float* __restrict__ c) {
    float s = l + r;
    float sn, cs;
    sincosf(s, &sn, &cs);
    float acc = c[4];
    acc = fmaf(c[3], l * r, acc);
    acc = fmaf(c[2], cs, acc);
    acc = fmaf(c[1], sn, acc);
    acc = fmaf(c[0], s,  acc);
    return acc;
}

// Compute the 7 nodes' folded coefficients into coef[7][8].
__global__ void coef_kernel(const float* __restrict__ w1, const float* __restrict__ b1,
                            const float* __restrict__ om1,
                            const float* __restrict__ w2, const float* __restrict__ b2,
                            const float* __restrict__ om2,
                            const float* __restrict__ w3, const float* __restrict__ b3,
                            const float* __restrict__ om3,
                            float* __restrict__ coef) {
    int t = threadIdx.x;
    if (t >= 7) return;
    const float* om;
    float w, b;
    if (t < 4)      { om = om3 + t * 4;       w = w3[t];     b = b3[t]; }
    else if (t < 6) { om = om2 + (t - 4) * 4; w = w2[t - 4]; b = b2[t - 4]; }
    else            { om = om1;               w = w1[0];     b = b1[0]; }
    float m  = fmaxf(fmaxf(om[0], om[1]), fmaxf(om[2], om[3]));
    float e0 = expf(om[0] - m), e1 = expf(om[1] - m);
    float e2 = expf(om[2] - m), e3 = expf(om[3] - m);
    float inv = w / (e0 + e1 + e2 + e3);
    coef[t * 8 + 0] = e0 * inv;
    coef[t * 8 + 1] = e1 * inv;
    coef[t * 8 + 2] = e2 * inv;
    coef[t * 8 + 3] = e3 * inv;
    coef[t * 8 + 4] = b;
    coef[t * 8 + 5] = 0.0f;
    coef[t * 8 + 6] = 0.0f;
    coef[t * 8 + 7] = 0.0f;
}

__device__ __forceinline__ float row_eval(const float xv[16],
                                          const float* __restrict__ lw,
                                          const float* __restrict__ lb,
                                          const float cf[7][5]) {
    float h[8];
#pragma unroll
    for (int l = 0; l < 8; ++l) {
        float acc = lb[l];
#pragma unroll
        for (int v = 0; v < 16; ++v) acc = fmaf(lw[l * 16 + v], xv[v], acc);
        h[l] = acc;
    }
    float g4[4];
#pragma unroll
    for (int nd = 0; nd < 4; ++nd) g4[nd] = node_eval(h[2 * nd], h[2 * nd + 1], cf[nd]);
    float g2[2];
    g2[0] = node_eval(g4[0], g4[1], cf[4]);
    g2[1] = node_eval(g4[2], g4[3], cf[5]);
    return node_eval(g2[0], g2[1], cf[6]);
}

__global__ __launch_bounds__(256) void tree_main(const float4* __restrict__ x,
                                                 const float* __restrict__ lw,
                                                 const float* __restrict__ lb,
                                                 const float* __restrict__ coef,
                                                 float* __restrict__ out, int N) {
    int n = blockIdx.x * 256 + threadIdx.x;
    if (n >= N) return;

    // wave-uniform coefficient reads -> scalar loads
    float cf[7][5];
#pragma unroll
    for (int nd = 0; nd < 7; ++nd)
#pragma unroll
        for (int k = 0; k < 5; ++k) cf[nd][k] = coef[nd * 8 + k];

    const float4* xp = x + (size_t)n * 4;
    float4 a0 = xp[0], a1 = xp[1], a2 = xp[2], a3 = xp[3];
    float xv[16] = {a0.x, a0.y, a0.z, a0.w, a1.x, a1.y, a1.z, a1.w,
                    a2.x, a2.y, a2.z, a2.w, a3.x, a3.y, a3.z, a3.w};

    out[n] = row_eval(xv, lw, lb, cf);
}

// Fallback if d_ws is unusable: compute coefficients per-thread (VALU, ~60 ops).
__global__ __launch_bounds__(256) void tree_main_inline(const float4* __restrict__ x,
                                                        const float* __restrict__ lw,
                                                        const float* __restrict__ lb,
                                                        const float* __restrict__ w1, const float* __restrict__ b1,
                                                        const float* __restrict__ om1,
                                                        const float* __restrict__ w2, const float* __restrict__ b2,
                                                        const float* __restrict__ om2,
                                                        const float* __restrict__ w3, const float* __restrict__ b3,
                                                        const float* __restrict__ om3,
                                                        float* __restrict__ out, int N) {
    int n = blockIdx.x * 256 + threadIdx.x;
    if (n >= N) return;

    float cf[7][5];
#pragma unroll
    for (int nd = 0; nd < 7; ++nd) {
        const float* om;
        float w, b;
        if (nd < 4)      { om = om3 + nd * 4;       w = w3[nd];     b = b3[nd]; }
        else if (nd < 6) { om = om2 + (nd - 4) * 4; w = w2[nd - 4]; b = b2[nd - 4]; }
        else             { om = om1;                w = w1[0];      b = b1[0]; }
        float m  = fmaxf(fmaxf(om[0], om[1]), fmaxf(om[2], om[3]));
        float e0 = __expf(om[0] - m), e1 = __expf(om[1] - m);
        float e2 = __expf(om[2] - m), e3 = __expf(om[3] - m);
        float inv = w / (e0 + e1 + e2 + e3);
        cf[nd][0] = e0 * inv; cf[nd][1] = e1 * inv;
        cf[nd][2] = e2 * inv; cf[nd][3] = e3 * inv;
        cf[nd][4] = b;
    }

    const float4* xp = x + (size_t)n * 4;
    float4 a0 = xp[0], a1 = xp[1], a2 = xp[2], a3 = xp[3];
    float xv[16] = {a0.x, a0.y, a0.z, a0.w, a1.x, a1.y, a1.z, a1.w,
                    a2.x, a2.y, a2.z, a2.w, a3.x, a3.y, a3.z, a3.w};

    out[n] = row_eval(xv, lw, lb, cf);
}

extern "C" void kernel_launch(void* const* d_in, const int* in_sizes, int n_in,
                              void* d_out, int out_size, void* d_ws, size_t ws_size,
                              hipStream_t stream) {
    const float* x      = (const float*)d_in[0];
    const float* leaf_w = (const float*)d_in[1];
    const float* leaf_b = (const float*)d_in[2];
    const float* w1     = (const float*)d_in[3];
    const float* b1     = (const float*)d_in[4];
    const float* om1    = (const float*)d_in[5];
    const float* w2     = (const float*)d_in[6];
    const float* b2     = (const float*)d_in[7];
    const float* om2    = (const float*)d_in[8];
    const float* w3     = (const float*)d_in[9];
    const float* b3     = (const float*)d_in[10];
    const float* om3    = (const float*)d_in[11];

    int N = in_sizes[0] / 16;
    int blocks = (N + 255) / 256;
    float* out = (float*)d_out;

    if (ws_size >= 7 * 8 * sizeof(float)) {
        float* coef = (float*)d_ws;
        coef_kernel<<<1, 64, 0, stream>>>(w1, b1, om1, w2, b2, om2, w3, b3, om3, coef);
        tree_main<<<blocks, 256, 0, stream>>>((const float4*)x, leaf_w, leaf_b, coef, out, N);
    } else {
        tree_main_inline<<<blocks, 256, 0, stream>>>((const float4*)x, leaf_w, leaf_b,
                                                     w1, b1, om1, w2, b2, om2, w3, b3, om3,
                                                     out, N);
    }
}